// Round 3
// baseline (352.552 us; speedup 1.0000x reference)
//
#include <hip/hip_runtime.h>

typedef __attribute__((ext_vector_type(8))) short s16x8;
typedef __attribute__((ext_vector_type(4))) float f32x4;
typedef __attribute__((ext_vector_type(8))) unsigned short u16x8;

#define GLB(p) ((const __attribute__((address_space(1))) void*)(p))
#define LDS(p) ((__attribute__((address_space(3))) void*)(p))

#define BAR() __builtin_amdgcn_s_barrier()
#define VMC(n) asm volatile("s_waitcnt vmcnt(" #n ")" ::: "memory")

__device__ __forceinline__ unsigned short f2bf(float f) {
  unsigned u = __float_as_uint(f);
  u += 0x7fffu + ((u >> 16) & 1u);   // round-to-nearest-even on bf16 boundary
  return (unsigned short)(u >> 16);
}

// ---------------------------------------------------------------------------
// Kernel 1 (merged): blocks [0,2048) do per-row top-k masking of W;
// blocks [2048, 2048+16384) convert x fp32->bf16. (unchanged)
// ---------------------------------------------------------------------------
__global__ __launch_bounds__(256) void prep_kernel(
    const float* __restrict__ W, unsigned short* __restrict__ Wb,
    const float* __restrict__ X, unsigned short* __restrict__ Xb) {
  __shared__ int hist[4096];
  __shared__ int scanres[2];
  __shared__ int wsum[4];
  const int tid  = threadIdx.x;

  if (blockIdx.x >= 2048) {
    // ---- convert path ----
    const size_t i = ((size_t)(blockIdx.x - 2048) * 256 + tid) * 8;
    const float4* xp = (const float4*)(X + i);
    const float4 a = xp[0], b = xp[1];
    u16x8 o;
    o[0] = f2bf(a.x); o[1] = f2bf(a.y); o[2] = f2bf(a.z); o[3] = f2bf(a.w);
    o[4] = f2bf(b.x); o[5] = f2bf(b.y); o[6] = f2bf(b.z); o[7] = f2bf(b.w);
    *(u16x8*)(Xb + i) = o;
    return;
  }

  // ---- top-k path: exact k=1024 of 2048 by |w|, lowest-index tie-break ----
  const int lane = tid & 63;
  const int wv   = tid >> 6;
  const int row  = blockIdx.x;
  const float* wr = W + (size_t)row * 2048;

  const float4 v0 = *(const float4*)(wr + tid * 8);
  const float4 v1 = *(const float4*)(wr + tid * 8 + 4);
  float val[8] = {v0.x, v0.y, v0.z, v0.w, v1.x, v1.y, v1.z, v1.w};
  unsigned key[8];
#pragma unroll
  for (int e = 0; e < 8; ++e) key[e] = __float_as_uint(val[e]) & 0x7fffffffu;

  unsigned prefix = 0;
  int rem = 1024;

  // Round 0: bits [31:20], 4096 bins
  for (int i = tid; i < 4096; i += 256) hist[i] = 0;
  __syncthreads();
#pragma unroll
  for (int e = 0; e < 8; ++e) atomicAdd(&hist[key[e] >> 20], 1);
  __syncthreads();
  if (wv == 0) {
    const int base = 4096 - (lane + 1) * 64;
    int s = 0;
    for (int b = 0; b < 64; ++b) s += hist[base + b];
    int cum = s;
#pragma unroll
    for (int off = 1; off < 64; off <<= 1) {
      int o = __shfl_up(cum, off, 64);
      if (lane >= off) cum += o;
    }
    const int cumex = cum - s;
    if (cumex < rem && rem <= cum) {
      int running = cumex;
      for (int b = 63; b >= 0; --b) {
        int h = hist[base + b];
        if (running + h >= rem) { scanres[0] = base + b; scanres[1] = rem - running; break; }
        running += h;
      }
    }
  }
  __syncthreads();
  prefix = ((unsigned)scanres[0]) << 20;
  rem = scanres[1];
  __syncthreads();

  // Round 1: bits [19:10], 1024 bins
  for (int i = tid; i < 1024; i += 256) hist[i] = 0;
  __syncthreads();
#pragma unroll
  for (int e = 0; e < 8; ++e)
    if ((key[e] >> 20) == (prefix >> 20)) atomicAdd(&hist[(key[e] >> 10) & 1023], 1);
  __syncthreads();
  if (wv == 0) {
    const int base = 1024 - (lane + 1) * 16;
    int s = 0;
    for (int b = 0; b < 16; ++b) s += hist[base + b];
    int cum = s;
#pragma unroll
    for (int off = 1; off < 64; off <<= 1) {
      int o = __shfl_up(cum, off, 64);
      if (lane >= off) cum += o;
    }
    const int cumex = cum - s;
    if (cumex < rem && rem <= cum) {
      int running = cumex;
      for (int b = 15; b >= 0; --b) {
        int h = hist[base + b];
        if (running + h >= rem) { scanres[0] = base + b; scanres[1] = rem - running; break; }
        running += h;
      }
    }
  }
  __syncthreads();
  prefix |= ((unsigned)scanres[0]) << 10;
  rem = scanres[1];
  __syncthreads();

  // Round 2: bits [9:0], 1024 bins
  for (int i = tid; i < 1024; i += 256) hist[i] = 0;
  __syncthreads();
#pragma unroll
  for (int e = 0; e < 8; ++e)
    if ((key[e] >> 10) == (prefix >> 10)) atomicAdd(&hist[key[e] & 1023], 1);
  __syncthreads();
  if (wv == 0) {
    const int base = 1024 - (lane + 1) * 16;
    int s = 0;
    for (int b = 0; b < 16; ++b) s += hist[base + b];
    int cum = s;
#pragma unroll
    for (int off = 1; off < 64; off <<= 1) {
      int o = __shfl_up(cum, off, 64);
      if (lane >= off) cum += o;
    }
    const int cumex = cum - s;
    if (cumex < rem && rem <= cum) {
      int running = cumex;
      for (int b = 15; b >= 0; --b) {
        int h = hist[base + b];
        if (running + h >= rem) { scanres[0] = base + b; scanres[1] = rem - running; break; }
        running += h;
      }
    }
  }
  __syncthreads();
  const unsigned T = prefix | (unsigned)scanres[0];
  rem = scanres[1];

  // Tie resolution: block-ordered exclusive scan of ==T counts
  int eqcnt = 0;
#pragma unroll
  for (int e = 0; e < 8; ++e) eqcnt += (key[e] == T) ? 1 : 0;
  int c = eqcnt;
#pragma unroll
  for (int off = 1; off < 64; off <<= 1) {
    int o = __shfl_up(c, off, 64);
    if (lane >= off) c += o;
  }
  if (lane == 63) wsum[wv] = c;
  __syncthreads();
  int wavebase = 0;
  for (int j = 0; j < wv; ++j) wavebase += wsum[j];
  const int myex = wavebase + c - eqcnt;

  u16x8 o;
  int r = 0;
#pragma unroll
  for (int e = 0; e < 8; ++e) {
    const bool iseq = (key[e] == T);
    const bool keep = (key[e] > T) || (iseq && (myex + r) < rem);
    r += iseq ? 1 : 0;
    o[e] = keep ? f2bf(val[e]) : (unsigned short)0;
  }
  *(u16x8*)(Wb + (size_t)row * 2048 + tid * 8) = o;
}

// ---------------------------------------------------------------------------
// Kernel 2: bf16 GEMM, C = A(MxK) * B(NxK)^T + bias, fp32 out.
// 256x256 tile, BK=64, 8 waves (2M x 4N). ONE barrier per K-tile:
//
//   tile t: stage ALL of tile t+1 -> buf^1 (8 global_load_lds / thread)
//           24 ds_reads + 64 MFMA (4 clusters), no internal barriers
//           VMC(0); BAR
//
// Rationale: barrier-per-phase forced all 8 waves into lockstep
// {all-read}/{all-MFMA} alternation (measured: tile time = LDS-demand +
// MFMA-demand, MfmaUtil 44%). With one barrier per tile, waves drift and
// stagger: one wave's MFMA overlaps another's ds_reads; within a wave the
// compiler's counted lgkmcnt waits let later read-groups drain under
// earlier MFMA clusters.
//
// Correctness:
//   WAR (stage into buf^1 vs tile t-1 readers of buf^1): a wave reaches the
//   end-of-(t-1) barrier only after its MFMAs issued, which required
//   compiler lgkmcnt waits => all its ds_reads of buf^1 completed. Stage of
//   t+1 is issued after that barrier. Safe.
//   RAW (reads of buf[bb] in tile t vs stage issued at start of t-1):
//   per-wave VMC(0) at end of t-1 retires those loads; BAR syncs waves.
// bLo kept in registers through cluster 4 (was re-read from LDS): 28 -> 24
// ds_reads per wave per tile. LDS swizzle (st_16x32 XOR), XCD chunk
// swizzle, staging-source inverse swizzle all unchanged.
// ---------------------------------------------------------------------------
__global__ __launch_bounds__(512, 2) void gemm_bt_kernel(
    const unsigned short* __restrict__ A,   // M x K bf16
    const unsigned short* __restrict__ B,   // N x K bf16
    const float* __restrict__ bias,         // N
    float* __restrict__ C) {                // M x N fp32
  constexpr int K = 2048;
  constexpr int N = 2048;
  constexpr int T = K / 64;                 // 32 K-tiles
  constexpr size_t HK = (size_t)128 * K;    // half-tile row stride in elements

  __shared__ __align__(16) char lds_[131072];

  const int tid = threadIdx.x;
  const int l   = tid & 63;
  const int wv  = tid >> 6;
  const int wm  = wv & 1;                   // 2 M-waves
  const int wn  = wv >> 1;                  // 4 N-waves

  // XCD chunk swizzle: 512 blocks, 8 XCDs, 64 contiguous tiles each (bijective)
  const int lin = blockIdx.x;
  const int o   = (lin & 7) * 64 + (lin >> 3);
  const int tm  = o >> 3;                   // 64 M-tiles
  const int tn  = o & 7;                    // 8  N-tiles

  // staging source coords: dest byte d (linear) -> logical (r,c) via inverse
  // swizzle (involution): off = d ^ (((d>>9)&1)<<5)
  int rS[2], cS[2];
#pragma unroll
  for (int e = 0; e < 2; ++e) {
    const int d   = (e * 512 + tid) * 16;
    const int off = d ^ (((d >> 9) & 1) << 5);
    rS[e] = ((off >> 11) << 4) | ((off >> 6) & 15);
    cS[e] = (((off >> 10) & 1) << 5) | (((off >> 4) & 3) << 3);
  }
  const unsigned short* const pA0 = A + (size_t)(tm * 256 + rS[0]) * K + cS[0];
  const unsigned short* const pA1 = A + (size_t)(tm * 256 + rS[1]) * K + cS[1];
  const unsigned short* const pB0 = B + (size_t)(tn * 256 + rS[0]) * K + cS[0];
  const unsigned short* const pB1 = B + (size_t)(tn * 256 + rS[1]) * K + cS[1];

  // issue one half-tile (2 x global_load_lds dwordx4 per thread)
  auto stage = [&](const unsigned short* g0, const unsigned short* g1, char* d) {
    __builtin_amdgcn_global_load_lds(GLB(g0), LDS(d + wv * 1024), 16, 0, 0);
    __builtin_amdgcn_global_load_lds(GLB(g1), LDS(d + 8192 + wv * 1024), 16, 0, 0);
  };

  // swizzled per-lane ds_read offset: logical (row=l&15, col=(l>>4)*8),
  // XOR bit5 when row&8  -> 4-wide bank spread, ~conflict-free b128 reads
  const int laneoff = (((l & 15) << 6) | ((l >> 4) << 4)) ^ ((l & 8) << 2);
  const char* const aRd = (const char*)lds_ + wm * 2048 + laneoff;
  const char* const bRd = (const char*)lds_ + 65536 + wn * 2048 + laneoff;

  f32x4 acc[8][4] = {};

  // ---- prologue: stage tile 0 into buf 0, drain, barrier ----
  stage(pA0,      pA1,      lds_);                      // (0,Ah0)
  stage(pA0 + HK, pA1 + HK, lds_ + 16384);              // (0,Ah1)
  stage(pB0,      pB1,      lds_ + 65536);              // (0,Bh0)
  stage(pB0 + HK, pB1 + HK, lds_ + 65536 + 16384);      // (0,Bh1)
  VMC(0);
  BAR();

  for (int t = 0; t < T; ++t) {
    const int bb = t & 1;
    const char* aT = aRd + bb * 32768;
    const char* bT = bRd + bb * 32768;
    char* nA = lds_ + (bb ^ 1) * 32768;
    char* nB = lds_ + 65536 + (bb ^ 1) * 32768;

    // stage whole tile t+1 into the other buffer (full tile of slack)
    if (t + 1 < T) {
      const size_t ko = (size_t)(t + 1) * 64;
      stage(pA0 + ko,      pA1 + ko,      nA);
      stage(pA0 + HK + ko, pA1 + HK + ko, nA + 16384);
      stage(pB0 + ko,      pB1 + ko,      nB);
      stage(pB0 + HK + ko, pB1 + HK + ko, nB + 16384);
    }

    s16x8 af[4][2], bLo[2][2], bHi[2][2];

    // ---- read group 1: cluster-1 operands first, then bHi prefetch ----
#pragma unroll
    for (int i = 0; i < 4; ++i)
      af[i][0] = *(const s16x8*)(aT + i * 4096);
#pragma unroll
    for (int j = 0; j < 2; ++j)
      bLo[j][0] = *(const s16x8*)(bT + j * 8192);
#pragma unroll
    for (int i = 0; i < 4; ++i)
      af[i][1] = *(const s16x8*)(aT + i * 4096 + 1024);
#pragma unroll
    for (int j = 0; j < 2; ++j)
      bLo[j][1] = *(const s16x8*)(bT + j * 8192 + 1024);
#pragma unroll
    for (int j = 0; j < 2; ++j) {
      bHi[j][0] = *(const s16x8*)(bT + 16384 + j * 8192);
      bHi[j][1] = *(const s16x8*)(bT + 16384 + j * 8192 + 1024);
    }

    // ---- cluster 1: aLo x bLo ----
    __builtin_amdgcn_s_setprio(1);
#pragma unroll
    for (int kk = 0; kk < 2; ++kk)
#pragma unroll
      for (int i = 0; i < 4; ++i)
#pragma unroll
        for (int j = 0; j < 2; ++j)
          acc[i][j] = __builtin_amdgcn_mfma_f32_16x16x32_bf16(af[i][kk], bLo[j][kk], acc[i][j], 0, 0, 0);
    __builtin_amdgcn_s_setprio(0);

    // ---- cluster 2: aLo x bHi ----
    __builtin_amdgcn_s_setprio(1);
#pragma unroll
    for (int kk = 0; kk < 2; ++kk)
#pragma unroll
      for (int i = 0; i < 4; ++i)
#pragma unroll
        for (int j = 0; j < 2; ++j)
          acc[i][j + 2] = __builtin_amdgcn_mfma_f32_16x16x32_bf16(af[i][kk], bHi[j][kk], acc[i][j + 2], 0, 0, 0);
    __builtin_amdgcn_s_setprio(0);

    // ---- read group 2: A-hi (af regs dead after cluster 2 issues) ----
#pragma unroll
    for (int i = 0; i < 4; ++i) {
      af[i][0] = *(const s16x8*)(aT + 16384 + i * 4096);
      af[i][1] = *(const s16x8*)(aT + 16384 + i * 4096 + 1024);
    }

    // ---- cluster 3: aHi x bHi ----
    __builtin_amdgcn_s_setprio(1);
#pragma unroll
    for (int kk = 0; kk < 2; ++kk)
#pragma unroll
      for (int i = 0; i < 4; ++i)
#pragma unroll
        for (int j = 0; j < 2; ++j)
          acc[i + 4][j + 2] = __builtin_amdgcn_mfma_f32_16x16x32_bf16(af[i][kk], bHi[j][kk], acc[i + 4][j + 2], 0, 0, 0);
    __builtin_amdgcn_s_setprio(0);

    // ---- cluster 4: aHi x bLo (bLo kept live, no re-read) ----
    __builtin_amdgcn_s_setprio(1);
#pragma unroll
    for (int kk = 0; kk < 2; ++kk)
#pragma unroll
      for (int i = 0; i < 4; ++i)
#pragma unroll
        for (int j = 0; j < 2; ++j)
          acc[i + 4][j] = __builtin_amdgcn_mfma_f32_16x16x32_bf16(af[i][kk], bLo[j][kk], acc[i + 4][j], 0, 0, 0);
    __builtin_amdgcn_s_setprio(0);

    VMC(0);          // own stage loads for tile t+1 landed
    BAR();           // everyone done reading buf[bb] & staging buf[bb^1]
  }

  // ---- epilogue: C/D layout col = lane&15, row = (lane>>4)*4 + reg ----
  float bv[4];
#pragma unroll
  for (int j = 0; j < 4; ++j)
    bv[j] = bias[tn * 256 + (4 * j + wn) * 16 + (l & 15)];

  const int crow0 = tm * 256 + wm * 16 + (l >> 4) * 4;   // + i*32 + r
  const int ccol0 = tn * 256 + wn * 16 + (l & 15);       // + j*64
  float* Cp = C + (size_t)crow0 * N + ccol0;
#pragma unroll
  for (int i = 0; i < 8; ++i)
#pragma unroll
    for (int j = 0; j < 4; ++j)
#pragma unroll
      for (int r = 0; r < 4; ++r)
        Cp[(size_t)(i * 32 + r) * N + j * 64] = acc[i][j][r] + bv[j];
}

extern "C" void kernel_launch(void* const* d_in, const int* in_sizes, int n_in,
                              void* d_out, int out_size, void* d_ws, size_t ws_size,
                              hipStream_t stream) {
  const float* x    = (const float*)d_in[0];   // [8,2048,2048]
  const float* w    = (const float*)d_in[1];   // [2048,2048]
  const float* bias = (const float*)d_in[2];   // [2048]
  float* out = (float*)d_out;                  // [8,2048,2048]

  constexpr int M = 8 * 2048;
  constexpr int N = 2048;
  constexpr int K = 2048;

  unsigned short* xb = (unsigned short*)d_ws;        // M*K bf16 = 67.1 MB
  unsigned short* wb = xb + (size_t)M * K;           // N*K bf16 =  8.4 MB

  const int conv_blocks = ((size_t)M * K) / (256 * 8);
  prep_kernel<<<2048 + conv_blocks, 256, 0, stream>>>(w, wb, x, xb);
  gemm_bt_kernel<<<(M / 256) * (N / 256), 512, 0, stream>>>(xb, wb, bias, out);
}